// Round 1
// baseline (635.992 us; speedup 1.0000x reference)
//
#include <hip/hip_runtime.h>
#include <hip/hip_bf16.h>

#define BB 8
#define CC 64
#define LL 4096
#define DD 128
#define NN 16
#define EPS 1e-5f

__device__ __forceinline__ float silu_f(float v) {
    return v / (1.f + __expf(-v));
}
__device__ __forceinline__ float softplus_f(float t) {
    return fmaxf(t, 0.f) + log1pf(__expf(-fabsf(t)));
}

// ---------------- K0: residual 1x1 conv + BN -> d_out ----------------
__global__ __launch_bounds__(256) void k_res(const float* __restrict__ x,
                                             const float* __restrict__ rw,
                                             const float* __restrict__ rbn,
                                             float* __restrict__ out) {
    int b = blockIdx.x >> 4;
    int s = ((blockIdx.x & 15) << 8) + threadIdx.x;
    const float* xb = x + (size_t)b * CC * LL;
    float xv[64];
#pragma unroll
    for (int ic = 0; ic < 64; ic++) xv[ic] = xb[ic * LL + s];
    for (int oc = 0; oc < 64; oc++) {
        float acc = 0.f;
#pragma unroll
        for (int ic = 0; ic < 64; ic++) acc = fmaf(xv[ic], rw[oc * 64 + ic], acc);
        float g = rbn[oc], be = rbn[64 + oc], m = rbn[128 + oc], v = rbn[192 + oc];
        float sc = g * rsqrtf(v + EPS);
        float sh = be - m * sc;
        out[((size_t)b * 64 + oc) * LL + s] = fmaf(acc, sc, sh);
    }
}

// ---------------- K1: in_proj GEMM -> xm_raw (B,128,L), z (B,128,L) ----------------
__global__ __launch_bounds__(256) void k_inproj(const float* __restrict__ x,
                                                const float* __restrict__ w,
                                                float* __restrict__ xm_raw,
                                                float* __restrict__ zraw) {
    int b = blockIdx.x >> 6;
    int l0 = (blockIdx.x & 63) << 6;
    int t = threadIdx.x & 63;
    int jg = threadIdx.x >> 6;     // wave-uniform
    int jb = __builtin_amdgcn_readfirstlane(jg);
    int l = l0 + t;
    const float* xb = x + (size_t)b * CC * LL;
    float xv[64];
#pragma unroll
    for (int c = 0; c < 64; c++) xv[c] = xb[c * LL + l];
    float* outbase = (jb < 2) ? (xm_raw + ((size_t)b * DD + jb * 64) * LL)
                              : (zraw + ((size_t)b * DD + (jb - 2) * 64) * LL);
    const float* wrow = w + jb * 64 * 64;
    for (int jj = 0; jj < 64; jj++) {
        float acc = 0.f;
#pragma unroll
        for (int c = 0; c < 64; c++) acc = fmaf(xv[c], wrow[jj * 64 + c], acc);
        outbase[(size_t)jj * LL + l] = acc;
    }
}

// ---------------- K1b: causal depthwise conv1d (k=4) + SiLU ----------------
__global__ __launch_bounds__(256) void k_conv1d(const float* __restrict__ xm_raw,
                                                const float* __restrict__ cw,
                                                const float* __restrict__ cb,
                                                float* __restrict__ xm_c) {
    int gid = blockIdx.x * 256 + threadIdx.x;   // B*D*L/4 threads
    int lg = gid & 1023;
    int bd = gid >> 10;
    int d = bd & 127;
    int l4 = lg * 4;
    const float* row = xm_raw + (size_t)bd * LL;
    float w0 = cw[d * 4], w1 = cw[d * 4 + 1], w2 = cw[d * 4 + 2], w3 = cw[d * 4 + 3];
    float bb = cb[d];
    float v[7];
#pragma unroll
    for (int k = 0; k < 7; k++) {
        int li = l4 - 3 + k;
        v[k] = (li >= 0) ? row[li] : 0.f;
    }
    float4 o;
    float* op = &o.x;
#pragma unroll
    for (int k = 0; k < 4; k++) {
        float s = bb + w0 * v[k] + w1 * v[k + 1] + w2 * v[k + 2] + w3 * v[k + 3];
        op[k] = silu_f(s);
    }
    *(float4*)&xm_c[(size_t)bd * LL + l4] = o;
}

// ---------------- K2: x_proj -> Bc,Cc (B,16,L); dt_proj+softplus -> dt (B,128,L) ----------------
__global__ __launch_bounds__(256) void k_xproj(const float* __restrict__ xm_c,
                                               const float* __restrict__ xw,
                                               const float* __restrict__ dtw,
                                               const float* __restrict__ dtb,
                                               float* __restrict__ Bc,
                                               float* __restrict__ Cc,
                                               float* __restrict__ dtO) {
    int b = blockIdx.x >> 4;
    int l = ((blockIdx.x & 15) << 8) + threadIdx.x;
    const float* xcol = xm_c + (size_t)b * DD * LL + l;
    float xv[128];
#pragma unroll
    for (int d = 0; d < 128; d++) xv[d] = xcol[(size_t)d * LL];
    float r0 = 0, r1 = 0, r2 = 0, r3 = 0;
#pragma unroll
    for (int d = 0; d < 128; d++) {
        r0 = fmaf(xv[d], xw[0 * 128 + d], r0);
        r1 = fmaf(xv[d], xw[1 * 128 + d], r1);
        r2 = fmaf(xv[d], xw[2 * 128 + d], r2);
        r3 = fmaf(xv[d], xw[3 * 128 + d], r3);
    }
    for (int jj = 4; jj < 36; jj++) {
        float a = 0.f;
#pragma unroll
        for (int d = 0; d < 128; d++) a = fmaf(xv[d], xw[jj * 128 + d], a);
        if (jj < 20) Bc[((size_t)b * NN + (jj - 4)) * LL + l] = a;
        else         Cc[((size_t)b * NN + (jj - 20)) * LL + l] = a;
    }
    for (int d = 0; d < 128; d++) {
        float t = dtb[d] + r0 * dtw[d * 4] + r1 * dtw[d * 4 + 1] +
                  r2 * dtw[d * 4 + 2] + r3 * dtw[d * 4 + 3];
        dtO[((size_t)b * DD + d) * LL + l] = softplus_f(t);
    }
}

// ---------------- Scan: chunked linear recurrence (16 chunks of 256) ----------------
#define NCH 16
#define CLEN 256

// Pass 1: per-chunk local scan from h=0; emit final h and product of dA.
__global__ __launch_bounds__(64) void k_scan1(const float* __restrict__ dt,
                                              const float* __restrict__ xm_c,
                                              const float* __restrict__ Bc,
                                              const float* __restrict__ A_log,
                                              float* __restrict__ chH,
                                              float* __restrict__ chP) {
    int bid = blockIdx.x;
    int ck = bid & 15;
    int dg = (bid >> 4) & 31;
    int b = bid >> 9;
    int lane = threadIdx.x;
    int q = lane >> 4, n = lane & 15;
    int d = dg * 4 + q;
    float a2 = -__expf(A_log[d * 16 + n]) * 1.4426950408889634f;
    const float* dtb_ = dt + ((size_t)b * DD + dg * 4) * LL;
    const float* xmb = xm_c + ((size_t)b * DD + dg * 4) * LL;
    const float* Bb = Bc + (size_t)b * NN * LL;
    __shared__ float s_dt[4 * 66], s_xm[4 * 66], s_B[16 * 66];
    float h = 0.f, P = 1.f;
    int l0 = ck * CLEN;
    for (int sub = 0; sub < CLEN / 64; sub++) {
        int ls = l0 + sub * 64;
        __syncthreads();
#pragma unroll
        for (int r = 0; r < 4; r++) {
            s_dt[r * 66 + lane] = dtb_[(size_t)r * LL + ls + lane];
            s_xm[r * 66 + lane] = xmb[(size_t)r * LL + ls + lane];
        }
#pragma unroll
        for (int nn = 0; nn < 16; nn++) s_B[nn * 66 + lane] = Bb[(size_t)nn * LL + ls + lane];
        __syncthreads();
#pragma unroll 8
        for (int i = 0; i < 64; i++) {
            float dtv = s_dt[q * 66 + i];
            float xv = s_xm[q * 66 + i];
            float Bv = s_B[n * 66 + i];
            float dA = exp2f(dtv * a2);
            h = fmaf(dA, h, dtv * xv * Bv);
            P *= dA;
        }
    }
    int base = (((b * 32 + dg) * NCH) + ck) * 64 + lane;
    chH[base] = h;
    chP[base] = P;
}

// Pass 2: compose chunk states sequentially -> h_init per chunk.
__global__ __launch_bounds__(64) void k_scan2(const float* __restrict__ chP,
                                              const float* __restrict__ chH,
                                              float* __restrict__ hinit) {
    int g = blockIdx.x;   // (b*32+dg)
    int lane = threadIdx.x;
    float H = 0.f;
    for (int ck = 0; ck < NCH; ck++) {
        int base = (g * NCH + ck) * 64 + lane;
        hinit[base] = H;
        H = chP[base] * H + chH[base];
    }
}

// Pass 3: re-scan with correct h_init, emit gated y = (ys + xm*Dp)*silu(z) in (B,128,L).
__global__ __launch_bounds__(64) void k_scan3(const float* __restrict__ dt,
                                              const float* __restrict__ xm_c,
                                              const float* __restrict__ Bc,
                                              const float* __restrict__ Cc,
                                              const float* __restrict__ zb_,
                                              const float* __restrict__ A_log,
                                              const float* __restrict__ Dp,
                                              const float* __restrict__ hinit,
                                              float* __restrict__ yg) {
    int bid = blockIdx.x;
    int ck = bid & 15;
    int dg = (bid >> 4) & 31;
    int b = bid >> 9;
    int lane = threadIdx.x;
    int q = lane >> 4, n = lane & 15;
    int d = dg * 4 + q;
    float a2 = -__expf(A_log[d * 16 + n]) * 1.4426950408889634f;
    float DpD = Dp[d];
    const float* dtb_ = dt + ((size_t)b * DD + dg * 4) * LL;
    const float* xmb = xm_c + ((size_t)b * DD + dg * 4) * LL;
    const float* zrow = zb_ + ((size_t)b * DD + dg * 4) * LL;
    const float* Bb = Bc + (size_t)b * NN * LL;
    const float* Cb = Cc + (size_t)b * NN * LL;
    __shared__ float s_dt[4 * 66], s_xm[4 * 66], s_z[4 * 66], s_B[16 * 66], s_C[16 * 66], t_y[4 * 66];
    float h = hinit[(((b * 32 + dg) * NCH) + ck) * 64 + lane];
    int l0 = ck * CLEN;
    for (int sub = 0; sub < CLEN / 64; sub++) {
        int ls = l0 + sub * 64;
        __syncthreads();
#pragma unroll
        for (int r = 0; r < 4; r++) {
            s_dt[r * 66 + lane] = dtb_[(size_t)r * LL + ls + lane];
            s_xm[r * 66 + lane] = xmb[(size_t)r * LL + ls + lane];
            s_z[r * 66 + lane] = zrow[(size_t)r * LL + ls + lane];
        }
#pragma unroll
        for (int nn = 0; nn < 16; nn++) {
            s_B[nn * 66 + lane] = Bb[(size_t)nn * LL + ls + lane];
            s_C[nn * 66 + lane] = Cb[(size_t)nn * LL + ls + lane];
        }
        __syncthreads();
#pragma unroll 4
        for (int i = 0; i < 64; i++) {
            float dtv = s_dt[q * 66 + i];
            float xv = s_xm[q * 66 + i];
            float Bv = s_B[n * 66 + i];
            float Cv = s_C[n * 66 + i];
            float dA = exp2f(dtv * a2);
            h = fmaf(dA, h, dtv * xv * Bv);
            float c = h * Cv;
            c += __shfl_xor(c, 1);
            c += __shfl_xor(c, 2);
            c += __shfl_xor(c, 4);
            c += __shfl_xor(c, 8);
            if (n == 0) {
                float zv = s_z[q * 66 + i];
                t_y[q * 66 + i] = (c + xv * DpD) * silu_f(zv);
            }
        }
        __syncthreads();
#pragma unroll
        for (int r = 0; r < 4; r++)
            yg[((size_t)b * DD + dg * 4 + r) * LL + ls + lane] = t_y[r * 66 + lane];
    }
}

// ---------------- K4: out_proj + PReLU -> out_tok (B,64,L) ----------------
__global__ __launch_bounds__(256) void k_outproj(const float* __restrict__ yg,
                                                 const float* __restrict__ wo,
                                                 const float* __restrict__ pre,
                                                 float* __restrict__ out_tok) {
    int b = blockIdx.x >> 4;
    int l = ((blockIdx.x & 15) << 8) + threadIdx.x;
    float yv[128];
#pragma unroll
    for (int d = 0; d < 128; d++) yv[d] = yg[((size_t)b * DD + d) * LL + l];
    float a = pre[0];
    for (int c = 0; c < 64; c++) {
        float acc = 0.f;
#pragma unroll
        for (int d = 0; d < 128; d++) acc = fmaf(yv[d], wo[c * 128 + d], acc);
        acc = acc >= 0.f ? acc : a * acc;
        out_tok[((size_t)b * 64 + c) * LL + l] = acc;
    }
}

// ---------------- K5/K6: 3x3 conv + BN + PReLU (+residual add) ----------------
// TR: input is out_tok with transposed-image semantics in[b][ic][p][q] = tok[q*64+p]
// ADD: add addp[] (the residual block already in d_out) before storing
template <bool TR, bool ADD>
__global__ __launch_bounds__(256) void k_conv3(const float* __restrict__ inp,
                                               const float* __restrict__ w,
                                               const float* __restrict__ bnp,
                                               const float* __restrict__ pre,
                                               const float* __restrict__ addp,
                                               float* __restrict__ outp) {
    int bid = blockIdx.x;
    int b = bid >> 6;
    int tile = bid & 63;
    int i0 = (tile >> 3) * 8;
    int j0 = (tile & 7) * 8;
    int pos = threadIdx.x & 63;
    int ocg = threadIdx.x >> 6;
    int ti = pos >> 3, tj = pos & 7;
    __shared__ float in_t[64][10][10];
    const float* ib = inp + (size_t)b * 64 * LL;
    for (int idx = threadIdx.x; idx < 6400; idx += 256) {
        int ic, pp, qq;
        if (TR) {
            pp = idx % 10;
            int rem = idx / 10;
            qq = rem % 10;
            ic = rem / 10;
        } else {
            qq = idx % 10;
            int rem = idx / 10;
            pp = rem % 10;
            ic = rem / 10;
        }
        int p = i0 - 1 + pp, qv = j0 - 1 + qq;
        float v = 0.f;
        if (p >= 0 && p < 64 && qv >= 0 && qv < 64)
            v = TR ? ib[ic * LL + qv * 64 + p] : ib[ic * LL + p * 64 + qv];
        in_t[ic][pp][qq] = v;
    }
    __syncthreads();
    float acc[16];
#pragma unroll
    for (int o = 0; o < 16; o++) acc[o] = 0.f;
    int oc0 = __builtin_amdgcn_readfirstlane(ocg) * 16;
    for (int ic = 0; ic < 64; ic++) {
        float iv[3][3];
#pragma unroll
        for (int di = 0; di < 3; di++)
#pragma unroll
            for (int dj = 0; dj < 3; dj++) iv[di][dj] = in_t[ic][ti + di][tj + dj];
#pragma unroll
        for (int o = 0; o < 16; o++) {
            const float* wr = w + ((size_t)(oc0 + o) * 64 + ic) * 9;
            float a = acc[o];
            a = fmaf(iv[0][0], wr[0], a);
            a = fmaf(iv[0][1], wr[1], a);
            a = fmaf(iv[0][2], wr[2], a);
            a = fmaf(iv[1][0], wr[3], a);
            a = fmaf(iv[1][1], wr[4], a);
            a = fmaf(iv[1][2], wr[5], a);
            a = fmaf(iv[2][0], wr[6], a);
            a = fmaf(iv[2][1], wr[7], a);
            a = fmaf(iv[2][2], wr[8], a);
            acc[o] = a;
        }
    }
    float pa = pre[0];
#pragma unroll
    for (int o = 0; o < 16; o++) {
        int oc = oc0 + o;
        float g = bnp[oc], be = bnp[64 + oc], m = bnp[128 + oc], vv = bnp[192 + oc];
        float sc = g * rsqrtf(vv + EPS);
        float sh = be - m * sc;
        float v = fmaf(acc[o], sc, sh);
        v = v >= 0.f ? v : pa * v;
        size_t addr = ((size_t)b * 64 + oc) * LL + (i0 + ti) * 64 + (j0 + tj);
        if (ADD) v += addp[addr];
        outp[addr] = v;
    }
}

extern "C" void kernel_launch(void* const* d_in, const int* in_sizes, int n_in,
                              void* d_out, int out_size, void* d_ws, size_t ws_size,
                              hipStream_t stream) {
    const float* x = (const float*)d_in[0];
    const float* in_proj_w = (const float*)d_in[1];
    const float* conv1d_w = (const float*)d_in[2];
    const float* conv1d_b = (const float*)d_in[3];
    const float* x_proj_w = (const float*)d_in[4];
    const float* dt_proj_w = (const float*)d_in[5];
    const float* dt_proj_b = (const float*)d_in[6];
    const float* A_log = (const float*)d_in[7];
    const float* Dp = (const float*)d_in[8];
    const float* out_proj_w = (const float*)d_in[9];
    const float* prelu_ssm = (const float*)d_in[10];
    const float* res_w = (const float*)d_in[11];
    const float* res_bn = (const float*)d_in[12];
    const float* conv1_w = (const float*)d_in[13];
    const float* bn1 = (const float*)d_in[14];
    const float* prelu1 = (const float*)d_in[15];
    const float* conv2_w = (const float*)d_in[16];
    const float* bn2 = (const float*)d_in[17];
    const float* prelu2 = (const float*)d_in[18];
    float* out = (float*)d_out;
    float* ws = (float*)d_ws;

    const size_t S = (size_t)BB * DD * LL;   // 4,194,304 floats
    float* xm_raw = ws;                      // later reused as ygate
    float* xm_c = ws + S;
    float* zbuf = ws + 2 * S;
    float* dtbuf = ws + 3 * S;               // later split into out_tok + img2
    float* ygate = ws;
    float* out_tok = ws + 3 * S;
    float* img2 = ws + 3 * S + (size_t)BB * 64 * LL;
    float* Bc = ws + 4 * S;
    float* Cc = Bc + (size_t)BB * NN * LL;
    float* chH = Cc + (size_t)BB * NN * LL;
    float* chP = chH + 256 * NCH * 64;
    float* hinit = chP + 256 * NCH * 64;

    // residual block -> d_out
    k_res<<<dim3(128), dim3(256), 0, stream>>>(x, res_w, res_bn, out);
    // in_proj
    k_inproj<<<dim3(512), dim3(256), 0, stream>>>(x, in_proj_w, xm_raw, zbuf);
    // depthwise conv1d + silu
    k_conv1d<<<dim3(4096), dim3(256), 0, stream>>>(xm_raw, conv1d_w, conv1d_b, xm_c);
    // x_proj + dt_proj + softplus
    k_xproj<<<dim3(128), dim3(256), 0, stream>>>(xm_c, x_proj_w, dt_proj_w, dt_proj_b, Bc, Cc, dtbuf);
    // chunked scan
    k_scan1<<<dim3(4096), dim3(64), 0, stream>>>(dtbuf, xm_c, Bc, A_log, chH, chP);
    k_scan2<<<dim3(256), dim3(64), 0, stream>>>(chP, chH, hinit);
    k_scan3<<<dim3(4096), dim3(64), 0, stream>>>(dtbuf, xm_c, Bc, Cc, zbuf, A_log, Dp, hinit, ygate);
    // out_proj + prelu
    k_outproj<<<dim3(128), dim3(256), 0, stream>>>(ygate, out_proj_w, prelu_ssm, out_tok);
    // conv1 (transposed input semantics) + bn1 + prelu1 -> img2
    k_conv3<true, false><<<dim3(512), dim3(256), 0, stream>>>(out_tok, conv1_w, bn1, prelu1, nullptr, img2);
    // conv2 + bn2 + prelu2 + residual add -> d_out
    k_conv3<false, true><<<dim3(512), dim3(256), 0, stream>>>(img2, conv2_w, bn2, prelu2, out, out);
}